// Round 2
// baseline (320.247 us; speedup 1.0000x reference)
//
#include <hip/hip_runtime.h>

// NeuS-style renderer sampling (all fp32):
//  inputs: ray_dirs (1,262144,3), cam_loc (1,3), t_rand (262144,64)
//  outputs (concat): new_samples (P,32,3), z_samples (P,32), weights (P,63)
//
// Round 5 (resubmit for measurement recovery — two infra failures):
// round-4 structure (thread-per-ray compute + LDS-staged, block-coalesced
// stores) + zbuf bank-conflict fix.
// zbuf ray stride 32 -> 33: merge-walk writes lds[tid*33+i] hit bank
// (tid+i)%32 (conflict-free for clustered i) instead of bank i%32
// (up to 32-way conflict, ~11x per-write cost). Read side switches from
// ds_read_b128 to 4x ds_read_b32 (33-stride is 16B-misaligned) - an order
// of magnitude cheaper than the write-side conflicts it removes.
// LDS 36 KB -> 37 KB; still 4 blocks/CU (4 x 37888 <= 160 KB).

static constexpr int NSTEPS = 64;
static constexpr int NIMP   = 32;

// ---------- pass 1a: per-block partial sums over hit rays ----------
__global__ __launch_bounds__(256) void si_partial_kernel(
    const float* __restrict__ rd, const float* __restrict__ cam,
    float* __restrict__ partial, int P)
{
  float cx = cam[0], cy = cam[1], cz = cam[2];
  float c2m = cx*cx + cy*cy + cz*cz - 1.0f;   // |cam|^2 - R^2, R=1
  float s0 = 0.f, s1 = 0.f, cnt = 0.f;
  int stride = gridDim.x * blockDim.x;
  for (int p = blockIdx.x * blockDim.x + threadIdx.x; p < P; p += stride){
    float dx = rd[3*p+0], dy = rd[3*p+1], dz = rd[3*p+2];
    float rcd = dx*cx + dy*cy + dz*cz;
    float under = rcd*rcd - c2m;
    if (under > 0.f){
      float sq = sqrtf(under);
      s0 += -sq - rcd; s1 += sq - rcd; cnt += 1.f;
    }
  }
  #pragma unroll
  for (int off = 32; off > 0; off >>= 1){
    s0  += __shfl_down(s0,  off, 64);
    s1  += __shfl_down(s1,  off, 64);
    cnt += __shfl_down(cnt, off, 64);
  }
  __shared__ float sh[3][4];
  int w = threadIdx.x >> 6;
  if ((threadIdx.x & 63) == 0){ sh[0][w] = s0; sh[1][w] = s1; sh[2][w] = cnt; }
  __syncthreads();
  if (threadIdx.x == 0){
    partial[blockIdx.x*3+0] = sh[0][0]+sh[0][1]+sh[0][2]+sh[0][3];
    partial[blockIdx.x*3+1] = sh[1][0]+sh[1][1]+sh[1][2]+sh[1][3];
    partial[blockIdx.x*3+2] = sh[2][0]+sh[2][1]+sh[2][2]+sh[2][3];
  }
}

// ---------- pass 1b: reduce partials -> ws[0..2] ----------
__global__ __launch_bounds__(256) void si_final_kernel(
    const float* __restrict__ partial, float* __restrict__ ws, int nblk)
{
  float s0 = 0.f, s1 = 0.f, cnt = 0.f;
  for (int b = threadIdx.x; b < nblk; b += 256){
    s0 += partial[3*b+0]; s1 += partial[3*b+1]; cnt += partial[3*b+2];
  }
  #pragma unroll
  for (int off = 32; off > 0; off >>= 1){
    s0  += __shfl_down(s0,  off, 64);
    s1  += __shfl_down(s1,  off, 64);
    cnt += __shfl_down(cnt, off, 64);
  }
  __shared__ float sh[3][4];
  int w = threadIdx.x >> 6;
  if ((threadIdx.x & 63) == 0){ sh[0][w] = s0; sh[1][w] = s1; sh[2][w] = cnt; }
  __syncthreads();
  if (threadIdx.x == 0){
    ws[0] = sh[0][0]+sh[0][1]+sh[0][2]+sh[0][3];
    ws[1] = sh[1][0]+sh[1][1]+sh[1][2]+sh[1][3];
    ws[2] = sh[2][0]+sh[2][1]+sh[2][2]+sh[2][3];
  }
}

// ---------- pass 2: thread per ray, LDS-staged coalesced stores ----------
// LDS map: [0..8447]  weights staging (8064 used) then zbuf[256][33] (8448)
//          [8448..9471] dbuf[256][4] (ray dirs, stride 4)
__global__ __launch_bounds__(256, 4) void render_main_kernel(
    const float* __restrict__ rd, const float* __restrict__ cam,
    const float* __restrict__ tr, const float* __restrict__ ws,
    float* __restrict__ out, int P)
{
  __shared__ float lds[9472];
  const int tid  = threadIdx.x;
  const int blk  = blockIdx.x;
  const int ray0 = blk * 256;
  const int nrays = min(256, P - ray0);
  const int p = min(ray0 + tid, P - 1);     // clamp; stores are range-guarded

  float cx = cam[0], cy = cam[1], cz = cam[2];
  float c2m = cx*cx + cy*cy + cz*cz - 1.0f;
  float dx = rd[3*p+0], dy = rd[3*p+1], dz = rd[3*p+2];
  lds[8448 + tid*4 + 0] = dx;               // dbuf (region disjoint from staging)
  lds[8448 + tid*4 + 1] = dy;
  lds[8448 + tid*4 + 2] = dz;

  float rcd = dx*cx + dy*cy + dz*cz;
  float under = rcd*rcd - c2m;
  float si0, si1;
  if (under > 0.f){
    float sq = sqrtf(under);
    si0 = -sq - rcd; si1 = sq - rcd;
  } else {
    float nh = fmaxf(ws[2], 1.0f);
    si0 = ws[0] / nh; si1 = ws[1] / nh;
  }
  float min_d = fmaxf(si0, 0.f), max_d = fmaxf(si1, 0.f);
  float range = max_d - min_d;
  float sdist = range * (1.0f / NSTEPS);

  const float4* tr4 = (const float4*)(tr + (size_t)p * NSTEPS);
  const float inv_s = 20.085536923187668f;  // exp(0.3*10)

  // ---- pass A: weights w[63] in regs + total T (steps on the fly) ----
  float w[NSTEPS-1];
  float T = 0.f, trans = 1.f;
  float4 v = tr4[0];
  float st = min_d + (v.x - 0.5f) * sdist;  // step 0 (linspace term = 0)
  float px = fmaf(st,dx,cx), py = fmaf(st,dy,cy), pz = fmaf(st,dz,cz);
  float c0 = 1.0f / (1.0f + __expf(-(sqrtf(px*px+py*py+pz*pz) - 0.5f) * inv_s));
  #pragma unroll
  for (int j = 1; j < NSTEPS; j++){
    if ((j & 3) == 0) v = tr4[j >> 2];
    float tj = ((j&3)==0) ? v.x : ((j&3)==1) ? v.y : ((j&3)==2) ? v.z : v.w;
    float sn = fmaf(range, (float)j * (1.0f/63.0f), min_d) + (tj - 0.5f) * sdist;
    float qx = fmaf(sn,dx,cx), qy = fmaf(sn,dy,cy), qz = fmaf(sn,dz,cz);
    float c1 = 1.0f / (1.0f + __expf(-(sqrtf(qx*qx+qy*qy+qz*qz) - 0.5f) * inv_s));
    float a = (c0 - c1 + 1e-8f) / (c0 + 1e-8f);
    a = fminf(fmaxf(a, 0.f), 1.0f);
    float wj = a * trans;
    w[j-1] = wj; T += wj;
    trans *= (1.0f - a + 1e-7f);
    c0 = c1;
  }
  T += 63.0f * 1e-8f;
  float invT = 1.0f / T;

  // ---- weights: stage+store in two 128-ray chunks (coalesced dwordx4) ----
  // chunk 0
  if (tid < 128){
    #pragma unroll
    for (int j = 0; j < 63; j++) lds[tid*63 + j] = w[j];
  }
  __syncthreads();
  {
    int cnt0 = min(128, nrays);
    if (cnt0 > 0){
      size_t base = (size_t)P*128 + (size_t)ray0*63;
      if (cnt0 == 128){
        float4* gw = (float4*)(out + base);
        const float4* lw = (const float4*)lds;
        #pragma unroll
        for (int it = 0; it < 8; it++){
          int idx = it*256 + tid;
          if (idx < 2016) gw[idx] = lw[idx];
        }
      } else {
        int dwn = cnt0 * 63;
        for (int idx = tid; idx < dwn; idx += 256) out[base + idx] = lds[idx];
      }
    }
  }
  __syncthreads();
  // chunk 1
  if (tid >= 128){
    #pragma unroll
    for (int j = 0; j < 63; j++) lds[(tid-128)*63 + j] = w[j];
  }
  __syncthreads();
  {
    int cnt1 = nrays - 128;
    if (cnt1 > 0){
      size_t base = (size_t)P*128 + ((size_t)ray0 + 128)*63;
      if (cnt1 == 128){
        float4* gw = (float4*)(out + base);
        const float4* lw = (const float4*)lds;
        #pragma unroll
        for (int it = 0; it < 8; it++){
          int idx = it*256 + tid;
          if (idx < 2016) gw[idx] = lw[idx];
        }
      } else {
        int dwn = cnt1 * 63;
        for (int idx = tid; idx < dwn; idx += 256) out[base + idx] = lds[idx];
      }
    }
  }
  __syncthreads();

  // ---- pass B: merge-walk; z -> zbuf[256][33] in LDS (stride 33 = no bank
  //      conflicts on the clustered-i writes; bank = (tid+i)%32) ----
  {
    float4 v2 = tr4[0];
    float sm = min_d + (v2.x - 0.5f) * sdist;
    float cdfm = 0.f;
    int i = 0;
    #pragma unroll
    for (int m = 0; m < NSTEPS-1; m++){
      int j = m + 1;
      if ((j & 3) == 0) v2 = tr4[j >> 2];
      float tj = ((j&3)==0) ? v2.x : ((j&3)==1) ? v2.y : ((j&3)==2) ? v2.z : v2.w;
      float sn = fmaf(range, (float)j * (1.0f/63.0f), min_d) + (tj - 0.5f) * sdist;
      float cdfn = cdfm + (w[m] + 1e-8f) * invT;
      while (i < NIMP){
        float u = (float)(2*i + 1) * (1.0f / 64.0f);
        if (!(u < cdfn)) break;             // searchsorted 'right'
        float denom = cdfn - cdfm;
        if (denom < 1e-8f) denom = 1.0f;
        float t = (u - cdfm) / denom;
        lds[tid*33 + i] = fmaf(t, sn - sm, sm);
        i++;
      }
      cdfm = cdfn; sm = sn;
    }
    while (i < NIMP){ lds[tid*33 + i] = sm; i++; }   // tail: z = steps[63]
  }
  __syncthreads();

  // ---- z_samples: coalesced dwordx4 out; LDS side is 4x b32 gather from
  //      the padded zbuf (33-stride is 16B-misaligned, scalar reads are
  //      conflict-free: bank = (r + s)%32 spans all banks) ----
  {
    int nz4 = nrays * 8;
    float4* gz = (float4*)(out + (size_t)P*96 + (size_t)ray0*32);
    #pragma unroll
    for (int it = 0; it < 8; it++){
      int idx = it*256 + tid;
      if (idx < nz4){
        int r  = idx >> 3;
        int s0 = (idx & 7) * 4;
        float4 o;
        o.x = lds[r*33 + s0 + 0];
        o.y = lds[r*33 + s0 + 1];
        o.z = lds[r*33 + s0 + 2];
        o.w = lds[r*33 + s0 + 3];
        gz[idx] = o;
      }
    }
  }

  // ---- new_samples: computed at store time from zbuf+dbuf, coalesced ----
  {
    int nn4 = nrays * 24;                    // 24 float4 per ray
    float4* gn = (float4*)(out + (size_t)ray0*96);
    #pragma unroll 4
    for (int it = 0; it < 24; it++){
      int idx4 = it*256 + tid;
      if (idx4 < nn4){
        int r   = idx4 / 24;
        int rem = idx4 - r*24;
        int e   = rem * 4;                   // element within ray region [0,96)
        int s   = e / 3;
        int c   = e - s*3;
        float4 o;
        float* op = &o.x;
        #pragma unroll
        for (int k = 0; k < 4; k++){
          float zz = lds[r*33 + s];
          float dd = lds[8448 + r*4 + c];
          float cc = (c == 0) ? cx : ((c == 1) ? cy : cz);
          op[k] = fmaf(zz, dd, cc);
          if (++c == 3){ c = 0; s++; }
        }
        gn[idx4] = o;
      }
    }
  }
}

extern "C" void kernel_launch(void* const* d_in, const int* in_sizes, int n_in,
                              void* d_out, int out_size, void* d_ws, size_t ws_size,
                              hipStream_t stream) {
  const float* rd  = (const float*)d_in[0];
  const float* cam = (const float*)d_in[1];
  const float* tr  = (const float*)d_in[2];
  float* out = (float*)d_out;
  float* ws  = (float*)d_ws;       // ws[0..2] = mean_si sums; ws+8.. = partials
  const int P = in_sizes[0] / 3;   // 262144 rays

  const int RBLK = 256;
  si_partial_kernel<<<RBLK, 256, 0, stream>>>(rd, cam, ws + 8, P);
  si_final_kernel<<<1, 256, 0, stream>>>(ws + 8, ws, RBLK);
  render_main_kernel<<<(P + 255) / 256, 256, 0, stream>>>(rd, cam, tr, ws, out, P);
}

// Round 3
// 319.219 us; speedup vs baseline: 1.0032x; 1.0032x over previous
//
#include <hip/hip_runtime.h>

// NeuS-style renderer sampling (all fp32):
//  inputs: ray_dirs (1,262144,3), cam_loc (1,3), t_rand (262144,64)
//  outputs (concat): new_samples (P,32,3), z_samples (P,32), weights (P,63)
//
// Round 6: spill fix. Round-5 profile showed VGPR_Count=64 (the 8-waves/EU
// budget) with ~130 MB of scratch round-trip (FETCH 235 MB vs ~137 ideal+tr2,
// WRITE 228 vs ~200): the allocator spilled w[63] chasing occupancy that LDS
// (37888 B -> 4 blocks/CU = 4 waves/EU) already forbids. amdgpu_waves_per_eu(4,4)
// pins the budget to 128 VGPRs so w[63] stays in registers. No occupancy loss.

static constexpr int NSTEPS = 64;
static constexpr int NIMP   = 32;

// ---------- pass 1a: per-block partial sums over hit rays ----------
__global__ __launch_bounds__(256) void si_partial_kernel(
    const float* __restrict__ rd, const float* __restrict__ cam,
    float* __restrict__ partial, int P)
{
  float cx = cam[0], cy = cam[1], cz = cam[2];
  float c2m = cx*cx + cy*cy + cz*cz - 1.0f;   // |cam|^2 - R^2, R=1
  float s0 = 0.f, s1 = 0.f, cnt = 0.f;
  int stride = gridDim.x * blockDim.x;
  for (int p = blockIdx.x * blockDim.x + threadIdx.x; p < P; p += stride){
    float dx = rd[3*p+0], dy = rd[3*p+1], dz = rd[3*p+2];
    float rcd = dx*cx + dy*cy + dz*cz;
    float under = rcd*rcd - c2m;
    if (under > 0.f){
      float sq = sqrtf(under);
      s0 += -sq - rcd; s1 += sq - rcd; cnt += 1.f;
    }
  }
  #pragma unroll
  for (int off = 32; off > 0; off >>= 1){
    s0  += __shfl_down(s0,  off, 64);
    s1  += __shfl_down(s1,  off, 64);
    cnt += __shfl_down(cnt, off, 64);
  }
  __shared__ float sh[3][4];
  int w = threadIdx.x >> 6;
  if ((threadIdx.x & 63) == 0){ sh[0][w] = s0; sh[1][w] = s1; sh[2][w] = cnt; }
  __syncthreads();
  if (threadIdx.x == 0){
    partial[blockIdx.x*3+0] = sh[0][0]+sh[0][1]+sh[0][2]+sh[0][3];
    partial[blockIdx.x*3+1] = sh[1][0]+sh[1][1]+sh[1][2]+sh[1][3];
    partial[blockIdx.x*3+2] = sh[2][0]+sh[2][1]+sh[2][2]+sh[2][3];
  }
}

// ---------- pass 1b: reduce partials -> ws[0..2] ----------
__global__ __launch_bounds__(256) void si_final_kernel(
    const float* __restrict__ partial, float* __restrict__ ws, int nblk)
{
  float s0 = 0.f, s1 = 0.f, cnt = 0.f;
  for (int b = threadIdx.x; b < nblk; b += 256){
    s0 += partial[3*b+0]; s1 += partial[3*b+1]; cnt += partial[3*b+2];
  }
  #pragma unroll
  for (int off = 32; off > 0; off >>= 1){
    s0  += __shfl_down(s0,  off, 64);
    s1  += __shfl_down(s1,  off, 64);
    cnt += __shfl_down(cnt, off, 64);
  }
  __shared__ float sh[3][4];
  int w = threadIdx.x >> 6;
  if ((threadIdx.x & 63) == 0){ sh[0][w] = s0; sh[1][w] = s1; sh[2][w] = cnt; }
  __syncthreads();
  if (threadIdx.x == 0){
    ws[0] = sh[0][0]+sh[0][1]+sh[0][2]+sh[0][3];
    ws[1] = sh[1][0]+sh[1][1]+sh[1][2]+sh[1][3];
    ws[2] = sh[2][0]+sh[2][1]+sh[2][2]+sh[2][3];
  }
}

// ---------- pass 2: thread per ray, LDS-staged coalesced stores ----------
// LDS map: [0..8447]  weights staging (8064 used) then zbuf[256][33] (8448)
//          [8448..9471] dbuf[256][4] (ray dirs, stride 4)
// amdgpu_waves_per_eu(4,4): LDS caps us at 4 blocks/CU (= 4 waves/EU) anyway;
// pin the allocator there so it gets the full 128-VGPR budget and keeps w[63]
// in registers instead of scratch (round-5: VGPR=64 + ~130 MB spill traffic).
__global__ __launch_bounds__(256)
__attribute__((amdgpu_waves_per_eu(4, 4)))
void render_main_kernel(
    const float* __restrict__ rd, const float* __restrict__ cam,
    const float* __restrict__ tr, const float* __restrict__ ws,
    float* __restrict__ out, int P)
{
  __shared__ float lds[9472];
  const int tid  = threadIdx.x;
  const int blk  = blockIdx.x;
  const int ray0 = blk * 256;
  const int nrays = min(256, P - ray0);
  const int p = min(ray0 + tid, P - 1);     // clamp; stores are range-guarded

  float cx = cam[0], cy = cam[1], cz = cam[2];
  float c2m = cx*cx + cy*cy + cz*cz - 1.0f;
  float dx = rd[3*p+0], dy = rd[3*p+1], dz = rd[3*p+2];
  lds[8448 + tid*4 + 0] = dx;               // dbuf (region disjoint from staging)
  lds[8448 + tid*4 + 1] = dy;
  lds[8448 + tid*4 + 2] = dz;

  float rcd = dx*cx + dy*cy + dz*cz;
  float under = rcd*rcd - c2m;
  float si0, si1;
  if (under > 0.f){
    float sq = sqrtf(under);
    si0 = -sq - rcd; si1 = sq - rcd;
  } else {
    float nh = fmaxf(ws[2], 1.0f);
    si0 = ws[0] / nh; si1 = ws[1] / nh;
  }
  float min_d = fmaxf(si0, 0.f), max_d = fmaxf(si1, 0.f);
  float range = max_d - min_d;
  float sdist = range * (1.0f / NSTEPS);

  const float4* tr4 = (const float4*)(tr + (size_t)p * NSTEPS);
  const float inv_s = 20.085536923187668f;  // exp(0.3*10)

  // ---- pass A: weights w[63] in regs + total T (steps on the fly) ----
  float w[NSTEPS-1];
  float T = 0.f, trans = 1.f;
  float4 v = tr4[0];
  float st = min_d + (v.x - 0.5f) * sdist;  // step 0 (linspace term = 0)
  float px = fmaf(st,dx,cx), py = fmaf(st,dy,cy), pz = fmaf(st,dz,cz);
  float c0 = 1.0f / (1.0f + __expf(-(sqrtf(px*px+py*py+pz*pz) - 0.5f) * inv_s));
  #pragma unroll
  for (int j = 1; j < NSTEPS; j++){
    if ((j & 3) == 0) v = tr4[j >> 2];
    float tj = ((j&3)==0) ? v.x : ((j&3)==1) ? v.y : ((j&3)==2) ? v.z : v.w;
    float sn = fmaf(range, (float)j * (1.0f/63.0f), min_d) + (tj - 0.5f) * sdist;
    float qx = fmaf(sn,dx,cx), qy = fmaf(sn,dy,cy), qz = fmaf(sn,dz,cz);
    float c1 = 1.0f / (1.0f + __expf(-(sqrtf(qx*qx+qy*qy+qz*qz) - 0.5f) * inv_s));
    float a = (c0 - c1 + 1e-8f) / (c0 + 1e-8f);
    a = fminf(fmaxf(a, 0.f), 1.0f);
    float wj = a * trans;
    w[j-1] = wj; T += wj;
    trans *= (1.0f - a + 1e-7f);
    c0 = c1;
  }
  T += 63.0f * 1e-8f;
  float invT = 1.0f / T;

  // ---- weights: stage+store in two 128-ray chunks (coalesced dwordx4) ----
  // chunk 0
  if (tid < 128){
    #pragma unroll
    for (int j = 0; j < 63; j++) lds[tid*63 + j] = w[j];
  }
  __syncthreads();
  {
    int cnt0 = min(128, nrays);
    if (cnt0 > 0){
      size_t base = (size_t)P*128 + (size_t)ray0*63;
      if (cnt0 == 128){
        float4* gw = (float4*)(out + base);
        const float4* lw = (const float4*)lds;
        #pragma unroll
        for (int it = 0; it < 8; it++){
          int idx = it*256 + tid;
          if (idx < 2016) gw[idx] = lw[idx];
        }
      } else {
        int dwn = cnt0 * 63;
        for (int idx = tid; idx < dwn; idx += 256) out[base + idx] = lds[idx];
      }
    }
  }
  __syncthreads();
  // chunk 1
  if (tid >= 128){
    #pragma unroll
    for (int j = 0; j < 63; j++) lds[(tid-128)*63 + j] = w[j];
  }
  __syncthreads();
  {
    int cnt1 = nrays - 128;
    if (cnt1 > 0){
      size_t base = (size_t)P*128 + ((size_t)ray0 + 128)*63;
      if (cnt1 == 128){
        float4* gw = (float4*)(out + base);
        const float4* lw = (const float4*)lds;
        #pragma unroll
        for (int it = 0; it < 8; it++){
          int idx = it*256 + tid;
          if (idx < 2016) gw[idx] = lw[idx];
        }
      } else {
        int dwn = cnt1 * 63;
        for (int idx = tid; idx < dwn; idx += 256) out[base + idx] = lds[idx];
      }
    }
  }
  __syncthreads();

  // ---- pass B: merge-walk; z -> zbuf[256][33] in LDS (stride 33 = no bank
  //      conflicts on the clustered-i writes; bank = (tid+i)%32) ----
  {
    float4 v2 = tr4[0];
    float sm = min_d + (v2.x - 0.5f) * sdist;
    float cdfm = 0.f;
    int i = 0;
    #pragma unroll
    for (int m = 0; m < NSTEPS-1; m++){
      int j = m + 1;
      if ((j & 3) == 0) v2 = tr4[j >> 2];
      float tj = ((j&3)==0) ? v2.x : ((j&3)==1) ? v2.y : ((j&3)==2) ? v2.z : v2.w;
      float sn = fmaf(range, (float)j * (1.0f/63.0f), min_d) + (tj - 0.5f) * sdist;
      float cdfn = cdfm + (w[m] + 1e-8f) * invT;
      while (i < NIMP){
        float u = (float)(2*i + 1) * (1.0f / 64.0f);
        if (!(u < cdfn)) break;             // searchsorted 'right'
        float denom = cdfn - cdfm;
        if (denom < 1e-8f) denom = 1.0f;
        float t = (u - cdfm) / denom;
        lds[tid*33 + i] = fmaf(t, sn - sm, sm);
        i++;
      }
      cdfm = cdfn; sm = sn;
    }
    while (i < NIMP){ lds[tid*33 + i] = sm; i++; }   // tail: z = steps[63]
  }
  __syncthreads();

  // ---- z_samples: coalesced dwordx4 out; LDS side is 4x b32 gather from
  //      the padded zbuf (33-stride is 16B-misaligned, scalar reads are
  //      conflict-free: bank = (r + s)%32 spans all banks) ----
  {
    int nz4 = nrays * 8;
    float4* gz = (float4*)(out + (size_t)P*96 + (size_t)ray0*32);
    #pragma unroll
    for (int it = 0; it < 8; it++){
      int idx = it*256 + tid;
      if (idx < nz4){
        int r  = idx >> 3;
        int s0 = (idx & 7) * 4;
        float4 o;
        o.x = lds[r*33 + s0 + 0];
        o.y = lds[r*33 + s0 + 1];
        o.z = lds[r*33 + s0 + 2];
        o.w = lds[r*33 + s0 + 3];
        gz[idx] = o;
      }
    }
  }

  // ---- new_samples: computed at store time from zbuf+dbuf, coalesced ----
  {
    int nn4 = nrays * 24;                    // 24 float4 per ray
    float4* gn = (float4*)(out + (size_t)ray0*96);
    #pragma unroll 4
    for (int it = 0; it < 24; it++){
      int idx4 = it*256 + tid;
      if (idx4 < nn4){
        int r   = idx4 / 24;
        int rem = idx4 - r*24;
        int e   = rem * 4;                   // element within ray region [0,96)
        int s   = e / 3;
        int c   = e - s*3;
        float4 o;
        float* op = &o.x;
        #pragma unroll
        for (int k = 0; k < 4; k++){
          float zz = lds[r*33 + s];
          float dd = lds[8448 + r*4 + c];
          float cc = (c == 0) ? cx : ((c == 1) ? cy : cz);
          op[k] = fmaf(zz, dd, cc);
          if (++c == 3){ c = 0; s++; }
        }
        gn[idx4] = o;
      }
    }
  }
}

extern "C" void kernel_launch(void* const* d_in, const int* in_sizes, int n_in,
                              void* d_out, int out_size, void* d_ws, size_t ws_size,
                              hipStream_t stream) {
  const float* rd  = (const float*)d_in[0];
  const float* cam = (const float*)d_in[1];
  const float* tr  = (const float*)d_in[2];
  float* out = (float*)d_out;
  float* ws  = (float*)d_ws;       // ws[0..2] = mean_si sums; ws+8.. = partials
  const int P = in_sizes[0] / 3;   // 262144 rays

  const int RBLK = 256;
  si_partial_kernel<<<RBLK, 256, 0, stream>>>(rd, cam, ws + 8, P);
  si_final_kernel<<<1, 256, 0, stream>>>(ws + 8, ws, RBLK);
  render_main_kernel<<<(P + 255) / 256, 256, 0, stream>>>(rd, cam, tr, ws, out, P);
}

// Round 4
// 310.106 us; speedup vs baseline: 1.0327x; 1.0294x over previous
//
#include <hip/hip_runtime.h>

// NeuS-style renderer sampling (all fp32):
//  inputs: ray_dirs (1,262144,3), cam_loc (1,3), t_rand (262144,64)
//  outputs (concat): new_samples (P,32,3), z_samples (P,32), weights (P,63)
//
// Round 7: WAVE-PER-RAY restructure. Rounds 5/6 showed the thread-per-ray
// design plateaus at ~130 us: w[63] retention forces AGPR/scratch traffic,
// zbuf LDS caps occupancy at 4 blocks/CU, and the pass-B tr re-read +
// 256B-strided row reads inflate EA traffic to 475 MB (ideal 270).
// Wave-per-ray: lane = step index. Sigmoids issue wave-wide; cumprod/CDF
// are 6-round shfl_up scans; searchsorted is a 6-probe bpermute binary
// count. No w[] array, no LDS, no barriers, tr read ONCE coalesced, all
// three outputs stored directly coalesced. ~35 VGPR, 0 LDS -> 32 waves/CU.

static constexpr int NSTEPS = 64;
static constexpr int NIMP   = 32;

// ---------- pass 1a: per-block partial sums over hit rays ----------
__global__ __launch_bounds__(256) void si_partial_kernel(
    const float* __restrict__ rd, const float* __restrict__ cam,
    float* __restrict__ partial, int P)
{
  float cx = cam[0], cy = cam[1], cz = cam[2];
  float c2m = cx*cx + cy*cy + cz*cz - 1.0f;   // |cam|^2 - R^2, R=1
  float s0 = 0.f, s1 = 0.f, cnt = 0.f;
  int stride = gridDim.x * blockDim.x;
  for (int p = blockIdx.x * blockDim.x + threadIdx.x; p < P; p += stride){
    float dx = rd[3*p+0], dy = rd[3*p+1], dz = rd[3*p+2];
    float rcd = dx*cx + dy*cy + dz*cz;
    float under = rcd*rcd - c2m;
    if (under > 0.f){
      float sq = sqrtf(under);
      s0 += -sq - rcd; s1 += sq - rcd; cnt += 1.f;
    }
  }
  #pragma unroll
  for (int off = 32; off > 0; off >>= 1){
    s0  += __shfl_down(s0,  off, 64);
    s1  += __shfl_down(s1,  off, 64);
    cnt += __shfl_down(cnt, off, 64);
  }
  __shared__ float sh[3][4];
  int w = threadIdx.x >> 6;
  if ((threadIdx.x & 63) == 0){ sh[0][w] = s0; sh[1][w] = s1; sh[2][w] = cnt; }
  __syncthreads();
  if (threadIdx.x == 0){
    partial[blockIdx.x*3+0] = sh[0][0]+sh[0][1]+sh[0][2]+sh[0][3];
    partial[blockIdx.x*3+1] = sh[1][0]+sh[1][1]+sh[1][2]+sh[1][3];
    partial[blockIdx.x*3+2] = sh[2][0]+sh[2][1]+sh[2][2]+sh[2][3];
  }
}

// ---------- pass 1b: reduce partials -> ws[0..2] ----------
__global__ __launch_bounds__(256) void si_final_kernel(
    const float* __restrict__ partial, float* __restrict__ ws, int nblk)
{
  float s0 = 0.f, s1 = 0.f, cnt = 0.f;
  for (int b = threadIdx.x; b < nblk; b += 256){
    s0 += partial[3*b+0]; s1 += partial[3*b+1]; cnt += partial[3*b+2];
  }
  #pragma unroll
  for (int off = 32; off > 0; off >>= 1){
    s0  += __shfl_down(s0,  off, 64);
    s1  += __shfl_down(s1,  off, 64);
    cnt += __shfl_down(cnt, off, 64);
  }
  __shared__ float sh[3][4];
  int w = threadIdx.x >> 6;
  if ((threadIdx.x & 63) == 0){ sh[0][w] = s0; sh[1][w] = s1; sh[2][w] = cnt; }
  __syncthreads();
  if (threadIdx.x == 0){
    ws[0] = sh[0][0]+sh[0][1]+sh[0][2]+sh[0][3];
    ws[1] = sh[1][0]+sh[1][1]+sh[1][2]+sh[1][3];
    ws[2] = sh[2][0]+sh[2][1]+sh[2][2]+sh[2][3];
  }
}

// ---------- pass 2: WAVE per ray; lane = step index ----------
__global__ __launch_bounds__(256) void render_wave_kernel(
    const float* __restrict__ rd, const float* __restrict__ cam,
    const float* __restrict__ tr, const float* __restrict__ ws,
    float* __restrict__ out, int P)
{
  const int lane = threadIdx.x & 63;
  const int wid  = (int)((blockIdx.x * blockDim.x + threadIdx.x) >> 6);
  const int nw   = (int)((gridDim.x * blockDim.x) >> 6);

  const float cx = cam[0], cy = cam[1], cz = cam[2];
  const float c2m = cx*cx + cy*cy + cz*cz - 1.0f;   // |cam|^2 - R^2
  const float nh = fmaxf(ws[2], 1.0f);
  const float m0 = ws[0] / nh, m1 = ws[1] / nh;     // mean si fallback

  const float inv_s = 20.085536923187668f;          // exp(0.3*10)
  const float jf = (float)lane * (1.0f/63.0f);      // linspace(0,1,64)[lane]
  const float u  = (float)(2*lane + 1) * (1.0f/64.0f); // lanes 0..31 meaningful

  // new_samples emission constants (hoisted): element e = z[e/3]*d[e%3]+c[e%3]
  const int e2 = 64 + lane;
  const int q1 = lane / 3, r1 = lane - 3*q1;        // e1 = lane (0..63)
  const int q2 = e2  / 3, r2 = e2  - 3*q2;          // e2 = 64+lane (lanes 0..31)

  for (int p = wid; p < P; p += nw){
    // ---- ray setup (wave-uniform; same-address loads broadcast) ----
    float dx = rd[3*p+0], dy = rd[3*p+1], dz = rd[3*p+2];
    float rcd = dx*cx + dy*cy + dz*cz;
    float under = rcd*rcd - c2m;
    float si0, si1;
    if (under > 0.f){                        // wave-uniform branch
      float sq = sqrtf(under);
      si0 = -sq - rcd; si1 = sq - rcd;
    } else {
      si0 = m0; si1 = m1;
    }
    float min_d = fmaxf(si0, 0.f), max_d = fmaxf(si1, 0.f);
    float range = max_d - min_d;
    float sdist = range * (1.0f/64.0f);      // (max-min)/N_STEPS

    // ---- per-lane step, sdf, sigmoid (one wave-instr per op) ----
    float t = tr[(size_t)p*64 + lane];       // coalesced 256B/wave, read ONCE
    float s = fmaf(range, jf, min_d) + (t - 0.5f) * sdist;
    float px = fmaf(s,dx,cx), py = fmaf(s,dy,cy), pz = fmaf(s,dz,cz);
    float c  = 1.0f / (1.0f + __expf(-(sqrtf(px*px+py*py+pz*pz) - 0.5f) * inv_s));

    // ---- alpha_j from (c_j, c_{j+1}); valid lanes 0..62 ----
    float cnx = __shfl_down(c, 1, 64);
    float a = (c - cnx + 1e-8f) / (c + 1e-8f);
    a = fminf(fmaxf(a, 0.f), 1.0f);

    // ---- trans = exclusive cumprod of (1-a+1e-7) via 6-round scan ----
    float f = (lane < 63) ? (1.0f - a + 1e-7f) : 1.0f;
    float incl = f;
    #pragma unroll
    for (int r = 1; r < 64; r <<= 1){
      float v = __shfl_up(incl, r, 64);
      if (lane >= r) incl *= v;
    }
    float trans = __shfl_up(incl, 1, 64);
    if (lane == 0) trans = 1.0f;

    // ---- weights (lanes 0..62): direct coalesced store, no retention ----
    float w = a * trans;
    if (lane < 63) out[(size_t)P*128 + (size_t)p*63 + lane] = w;

    // ---- normalized CDF via 6-round add scan ----
    float wp = (lane < 63) ? (w + 1e-8f) : 0.0f;
    float D = wp;
    #pragma unroll
    for (int r = 1; r < 64; r <<= 1){
      float v = __shfl_up(D, r, 64);
      if (lane >= r) D += v;
    }
    float Tp = __shfl(D, 62, 64);            // sum over 63 entries
    float invT = 1.0f / Tp;
    D *= invT;                                // D_j = cdf_full[j+1], D_62 = 1
    if (lane == 63) D = 2.0f;                 // sentinel for binary count

    // ---- searchsorted(cdf_full, u, 'right'): js = #{k<=62: D_k <= u} ----
    int js = 0;
    #pragma unroll
    for (int r = 32; r >= 1; r >>= 1){
      float v = __shfl(D, js + r - 1, 64);    // dynamic-index bpermute
      if (v <= u) js += r;
    }
    // lanes 0..31: js in [0,62]  (D_62 = 1 > u = (2i+1)/64 <= 63/64)
    float Db = (js > 0) ? __shfl(D, js - 1, 64) : 0.0f;
    float Da = __shfl(D, js, 64);
    float sb = __shfl(s, js, 64);
    float sa = __shfl(s, js + 1, 64);
    float den = Da - Db;
    if (den < 1e-8f) den = 1.0f;
    float tq = (u - Db) / den;
    float z  = fmaf(tq, sa - sb, sb);
    if (lane < 32) out[(size_t)P*96 + (size_t)p*32 + lane] = z;

    // ---- new_samples: 96 floats = cam + z[e/3]*dir[e%3]; two stores ----
    float z1 = __shfl(z, q1, 64);             // q1 <= 21, valid z lanes
    float dd1 = (r1 == 0) ? dx : ((r1 == 1) ? dy : dz);
    float cc1 = (r1 == 0) ? cx : ((r1 == 1) ? cy : cz);
    out[(size_t)p*96 + lane] = fmaf(z1, dd1, cc1);
    if (lane < 32){
      float z2 = __shfl(z, q2, 64);           // q2 <= 31, valid z lanes
      float dd2 = (r2 == 0) ? dx : ((r2 == 1) ? dy : dz);
      float cc2 = (r2 == 0) ? cx : ((r2 == 1) ? cy : cz);
      out[(size_t)p*96 + e2] = fmaf(z2, dd2, cc2);
    }
  }
}

extern "C" void kernel_launch(void* const* d_in, const int* in_sizes, int n_in,
                              void* d_out, int out_size, void* d_ws, size_t ws_size,
                              hipStream_t stream) {
  const float* rd  = (const float*)d_in[0];
  const float* cam = (const float*)d_in[1];
  const float* tr  = (const float*)d_in[2];
  float* out = (float*)d_out;
  float* ws  = (float*)d_ws;       // ws[0..2] = mean_si sums; ws+8.. = partials
  const int P = in_sizes[0] / 3;   // 262144 rays

  const int RBLK = 256;
  si_partial_kernel<<<RBLK, 256, 0, stream>>>(rd, cam, ws + 8, P);
  si_final_kernel<<<1, 256, 0, stream>>>(ws + 8, ws, RBLK);
  // 2048 blocks = 8 blocks/CU, 32 waves/CU (0 LDS, ~35 VGPR): full occupancy.
  // Each wave grid-strides over rays (8192 waves -> 32 rays/wave at P=262144).
  render_wave_kernel<<<2048, 256, 0, stream>>>(rd, cam, tr, ws, out, P);
}

// Round 5
// 303.877 us; speedup vs baseline: 1.0539x; 1.0205x over previous
//
#include <hip/hip_runtime.h>

// NeuS-style renderer sampling (all fp32):
//  inputs: ray_dirs (1,262144,3), cam_loc (1,3), t_rand (262144,64)
//  outputs (concat): new_samples (P,32,3), z_samples (P,32), weights (P,63)
//
// Round 8: wave-per-ray + DPP scans. Round-7 (wave-per-ray with shfl scans)
// only gained ~5 us e2e: ~27 ds_bpermute per ray (two 6-round shfl scans +
// search + gathers) put ~69 us of serialized traffic on the LDS pipe
// (27*262144/256CU*~6cyc). This round moves both scans and the +-1 shifts
// to the VALU pipe via DPP (row_shr:1/2/4/8 + row_bcast:15/31, wf_shl/shr:1)
// -- 0 DS ops, 0 exec-mask churn. Only the dynamic-index binary search and
// interpolation gathers remain bpermute (12 DS ops/ray, ~31 us pipe time,
// overlapped with the ~43 us memory floor).

static constexpr int NSTEPS = 64;
static constexpr int NIMP   = 32;

// DPP update: dest = (src permuted by CTRL) where valid+row-selected, else OLD.
// CTRL: 0x111/0x112/0x114/0x118 = row_shr:1/2/4/8; 0x142 row_bcast:15;
//       0x143 row_bcast:31; 0x130 wf_shl:1 (lane i <- i+1); 0x138 wf_shr:1.
template<int CTRL, int RM>
__device__ __forceinline__ float upd_dpp_f(float old, float src){
  return __int_as_float(__builtin_amdgcn_update_dpp(
      __float_as_int(old), __float_as_int(src), CTRL, RM, 0xF, false));
}

// inclusive 64-lane scans, all on the VALU pipe (identity fills via OLD)
__device__ __forceinline__ float mul_scan64(float x){
  x *= upd_dpp_f<0x111,0xF>(1.0f, x);
  x *= upd_dpp_f<0x112,0xF>(1.0f, x);
  x *= upd_dpp_f<0x114,0xF>(1.0f, x);
  x *= upd_dpp_f<0x118,0xF>(1.0f, x);
  x *= upd_dpp_f<0x142,0xa>(1.0f, x);   // row1,3 *= total(row0 / row2)
  x *= upd_dpp_f<0x143,0xc>(1.0f, x);   // rows2,3 *= total(lanes 0..31)
  return x;
}
__device__ __forceinline__ float add_scan64(float x){
  x += upd_dpp_f<0x111,0xF>(0.0f, x);
  x += upd_dpp_f<0x112,0xF>(0.0f, x);
  x += upd_dpp_f<0x114,0xF>(0.0f, x);
  x += upd_dpp_f<0x118,0xF>(0.0f, x);
  x += upd_dpp_f<0x142,0xa>(0.0f, x);
  x += upd_dpp_f<0x143,0xc>(0.0f, x);
  return x;
}

// ---------- pass 1a: per-block partial sums over hit rays ----------
__global__ __launch_bounds__(256) void si_partial_kernel(
    const float* __restrict__ rd, const float* __restrict__ cam,
    float* __restrict__ partial, int P)
{
  float cx = cam[0], cy = cam[1], cz = cam[2];
  float c2m = cx*cx + cy*cy + cz*cz - 1.0f;   // |cam|^2 - R^2, R=1
  float s0 = 0.f, s1 = 0.f, cnt = 0.f;
  int stride = gridDim.x * blockDim.x;
  for (int p = blockIdx.x * blockDim.x + threadIdx.x; p < P; p += stride){
    float dx = rd[3*p+0], dy = rd[3*p+1], dz = rd[3*p+2];
    float rcd = dx*cx + dy*cy + dz*cz;
    float under = rcd*rcd - c2m;
    if (under > 0.f){
      float sq = sqrtf(under);
      s0 += -sq - rcd; s1 += sq - rcd; cnt += 1.f;
    }
  }
  #pragma unroll
  for (int off = 32; off > 0; off >>= 1){
    s0  += __shfl_down(s0,  off, 64);
    s1  += __shfl_down(s1,  off, 64);
    cnt += __shfl_down(cnt, off, 64);
  }
  __shared__ float sh[3][4];
  int w = threadIdx.x >> 6;
  if ((threadIdx.x & 63) == 0){ sh[0][w] = s0; sh[1][w] = s1; sh[2][w] = cnt; }
  __syncthreads();
  if (threadIdx.x == 0){
    partial[blockIdx.x*3+0] = sh[0][0]+sh[0][1]+sh[0][2]+sh[0][3];
    partial[blockIdx.x*3+1] = sh[1][0]+sh[1][1]+sh[1][2]+sh[1][3];
    partial[blockIdx.x*3+2] = sh[2][0]+sh[2][1]+sh[2][2]+sh[2][3];
  }
}

// ---------- pass 1b: reduce partials -> ws[0..2] ----------
__global__ __launch_bounds__(256) void si_final_kernel(
    const float* __restrict__ partial, float* __restrict__ ws, int nblk)
{
  float s0 = 0.f, s1 = 0.f, cnt = 0.f;
  for (int b = threadIdx.x; b < nblk; b += 256){
    s0 += partial[3*b+0]; s1 += partial[3*b+1]; cnt += partial[3*b+2];
  }
  #pragma unroll
  for (int off = 32; off > 0; off >>= 1){
    s0  += __shfl_down(s0,  off, 64);
    s1  += __shfl_down(s1,  off, 64);
    cnt += __shfl_down(cnt, off, 64);
  }
  __shared__ float sh[3][4];
  int w = threadIdx.x >> 6;
  if ((threadIdx.x & 63) == 0){ sh[0][w] = s0; sh[1][w] = s1; sh[2][w] = cnt; }
  __syncthreads();
  if (threadIdx.x == 0){
    ws[0] = sh[0][0]+sh[0][1]+sh[0][2]+sh[0][3];
    ws[1] = sh[1][0]+sh[1][1]+sh[1][2]+sh[1][3];
    ws[2] = sh[2][0]+sh[2][1]+sh[2][2]+sh[2][3];
  }
}

// ---------- pass 2: WAVE per ray; lane = step index ----------
__global__ __launch_bounds__(256) void render_wave_kernel(
    const float* __restrict__ rd, const float* __restrict__ cam,
    const float* __restrict__ tr, const float* __restrict__ ws,
    float* __restrict__ out, int P)
{
  const int lane = threadIdx.x & 63;
  const int wid  = (int)((blockIdx.x * blockDim.x + threadIdx.x) >> 6);
  const int nw   = (int)((gridDim.x * blockDim.x) >> 6);

  const float cx = cam[0], cy = cam[1], cz = cam[2];
  const float c2m = cx*cx + cy*cy + cz*cz - 1.0f;   // |cam|^2 - R^2
  const float nh = fmaxf(ws[2], 1.0f);
  const float m0 = ws[0] / nh, m1 = ws[1] / nh;     // mean si fallback

  const float inv_s = 20.085536923187668f;          // exp(0.3*10)
  const float jf = (float)lane * (1.0f/63.0f);      // linspace(0,1,64)[lane]
  const float u  = (float)(2*lane + 1) * (1.0f/64.0f); // lanes 0..31 meaningful

  // new_samples emission constants: element e -> z[e/3]*d[e%3]+c[e%3]
  const int e2 = 64 + lane;
  const int q1 = lane / 3, r1 = lane - 3*q1;        // e1 = lane (0..63)
  const int q2 = e2  / 3, r2 = e2  - 3*q2;          // e2 = 64+lane (lanes 0..31)

  for (int p = wid; p < P; p += nw){
    // ---- ray setup (wave-uniform; same-address loads broadcast) ----
    float dx = rd[3*p+0], dy = rd[3*p+1], dz = rd[3*p+2];
    float rcd = dx*cx + dy*cy + dz*cz;
    float under = rcd*rcd - c2m;
    float si0, si1;
    if (under > 0.f){                        // wave-uniform branch
      float sq = sqrtf(under);
      si0 = -sq - rcd; si1 = sq - rcd;
    } else {
      si0 = m0; si1 = m1;
    }
    float min_d = fmaxf(si0, 0.f), max_d = fmaxf(si1, 0.f);
    float range = max_d - min_d;
    float sdist = range * (1.0f/64.0f);      // (max-min)/N_STEPS

    // ---- per-lane step, sdf, sigmoid (one wave-instr per op) ----
    float t = tr[(size_t)p*64 + lane];       // coalesced 256B/wave, read ONCE
    float s = fmaf(range, jf, min_d) + (t - 0.5f) * sdist;
    float px = fmaf(s,dx,cx), py = fmaf(s,dy,cy), pz = fmaf(s,dz,cz);
    float c  = 1.0f / (1.0f + __expf(-(sqrtf(px*px+py*py+pz*pz) - 0.5f) * inv_s));

    // ---- alpha_j from (c_j, c_{j+1}); valid lanes 0..62 (DPP wf_shl:1) ----
    float cnx = upd_dpp_f<0x130,0xF>(c, c);  // lane i <- c[i+1]; lane63 = c
    float a = (c - cnx + 1e-8f) / (c + 1e-8f);
    a = fminf(fmaxf(a, 0.f), 1.0f);

    // ---- trans = exclusive cumprod of (1-a+1e-7), DPP mul-scan ----
    float f = (lane < 63) ? (1.0f - a + 1e-7f) : 1.0f;
    float incl = mul_scan64(f);
    float trans = upd_dpp_f<0x138,0xF>(1.0f, incl);  // shift up 1; lane0 = 1

    // ---- weights (lanes 0..62): direct coalesced store, no retention ----
    float w = a * trans;
    if (lane < 63) out[(size_t)P*128 + (size_t)p*63 + lane] = w;

    // ---- normalized CDF via DPP add-scan ----
    float wp = (lane < 63) ? (w + 1e-8f) : 0.0f;
    float D = add_scan64(wp);
    float Tp = __shfl(D, 62, 64);            // readlane broadcast (no DS)
    float invT = 1.0f / Tp;
    D *= invT;                                // D_j = cdf_full[j+1], D_62 = 1
    if (lane == 63) D = 2.0f;                 // sentinel for binary count

    // ---- searchsorted(cdf_full, u, 'right'): js = #{k<=62: D_k <= u} ----
    int js = 0;
    #pragma unroll
    for (int r = 32; r >= 1; r >>= 1){
      float v = __shfl(D, js + r - 1, 64);    // dynamic-index bpermute
      if (v <= u) js += r;
    }
    // lanes 0..31: js in [0,62]  (D_62 = 1 > u = (2i+1)/64 <= 63/64)
    float Db = (js > 0) ? __shfl(D, js - 1, 64) : 0.0f;
    float Da = __shfl(D, js, 64);
    float sb = __shfl(s, js, 64);
    float sa = __shfl(s, js + 1, 64);
    float den = Da - Db;
    if (den < 1e-8f) den = 1.0f;
    float tq = (u - Db) / den;
    float z  = fmaf(tq, sa - sb, sb);
    if (lane < 32) out[(size_t)P*96 + (size_t)p*32 + lane] = z;

    // ---- new_samples: 96 floats = cam + z[e/3]*dir[e%3]; two stores ----
    float z1 = __shfl(z, q1, 64);             // q1 <= 21, valid z lanes
    float dd1 = (r1 == 0) ? dx : ((r1 == 1) ? dy : dz);
    float cc1 = (r1 == 0) ? cx : ((r1 == 1) ? cy : cz);
    out[(size_t)p*96 + lane] = fmaf(z1, dd1, cc1);
    if (lane < 32){
      float z2 = __shfl(z, q2, 64);           // q2 <= 31, valid z lanes
      float dd2 = (r2 == 0) ? dx : ((r2 == 1) ? dy : dz);
      float cc2 = (r2 == 0) ? cx : ((r2 == 1) ? cy : cz);
      out[(size_t)p*96 + e2] = fmaf(z2, dd2, cc2);
    }
  }
}

extern "C" void kernel_launch(void* const* d_in, const int* in_sizes, int n_in,
                              void* d_out, int out_size, void* d_ws, size_t ws_size,
                              hipStream_t stream) {
  const float* rd  = (const float*)d_in[0];
  const float* cam = (const float*)d_in[1];
  const float* tr  = (const float*)d_in[2];
  float* out = (float*)d_out;
  float* ws  = (float*)d_ws;       // ws[0..2] = mean_si sums; ws+8.. = partials
  const int P = in_sizes[0] / 3;   // 262144 rays

  const int RBLK = 256;
  si_partial_kernel<<<RBLK, 256, 0, stream>>>(rd, cam, ws + 8, P);
  si_final_kernel<<<1, 256, 0, stream>>>(ws + 8, ws, RBLK);
  // 2048 blocks = 8 blocks/CU, 32 waves/CU (0 LDS): full occupancy.
  render_wave_kernel<<<2048, 256, 0, stream>>>(rd, cam, tr, ws, out, P);
}